// Round 2
// baseline (4649.374 us; speedup 1.0000x reference)
//
#include <hip/hip_runtime.h>

#define NODES 100000
#define NBKT 782            // ceil(100000/128) buckets of 128 cols
#define HCHUNK 8192         // edges per bucket_hist block
#define FCHUNK 4096         // edges per bucket_fill block (256 thr x 16)

// ---------------- small utils ----------------

__global__ __launch_bounds__(256) void zero_k(int* __restrict__ p, int n) {
  int i = blockIdx.x * 256 + threadIdx.x;
  if (i < n) p[i] = 0;
}

// ---------------- bucket build ----------------

__global__ __launch_bounds__(256) void bucket_hist_k(const int* __restrict__ col,
                                                     int* __restrict__ bcnt, int E) {
  __shared__ int h[NBKT];
  int t = threadIdx.x;
  for (int i = t; i < NBKT; i += 256) h[i] = 0;
  __syncthreads();
  int base = blockIdx.x * HCHUNK;
#pragma unroll 4
  for (int j = 0; j < HCHUNK / 256; ++j) {
    int i = base + j * 256 + t;
    if (i < E) atomicAdd(&h[col[i] >> 7], 1);
  }
  __syncthreads();
  for (int i = t; i < NBKT; i += 256) {
    int c = h[i];
    if (c) atomicAdd(&bcnt[i], c);
  }
}

// single-block exclusive scan over NBKT (<=1024) bucket counts -> offsets + cursors
__global__ __launch_bounds__(256) void bscan_k(const int* __restrict__ bcnt,
                                               int* __restrict__ boffs,
                                               int* __restrict__ bcurs, int nb, int E) {
  __shared__ int lds[256];
  int t = threadIdx.x;
  int base = t * 4;
  int v[4];
#pragma unroll
  for (int j = 0; j < 4; ++j) v[j] = (base + j < nb) ? bcnt[base + j] : 0;
  int s = v[0] + v[1] + v[2] + v[3];
  lds[t] = s;
  __syncthreads();
  for (int off = 1; off < 256; off <<= 1) {
    int y = (t >= off) ? lds[t - off] : 0;
    __syncthreads();
    lds[t] += y;
    __syncthreads();
  }
  int excl = lds[t] - s;
#pragma unroll
  for (int j = 0; j < 4; ++j) {
    int i = base + j;
    if (i < nb) { boffs[i] = excl; bcurs[i] = excl; }
    excl += v[j];
  }
  if (t == 255) boffs[nb] = E;
}

// scatter packed records (colLow<<17 | row) into bucket regions.
// block-aggregated: LDS local ranks + one chunk-reservation atomic per (block,bucket).
__global__ __launch_bounds__(256) void bucket_fill_k(const int* __restrict__ row,
                                                     const int* __restrict__ col,
                                                     int* __restrict__ bcurs,
                                                     unsigned int* __restrict__ recs, int E) {
  __shared__ int lcnt[NBKT];
  __shared__ int lbase[NBKT];
  int t = threadIdx.x;
  int base = blockIdx.x * FCHUNK;
  for (int i = t; i < NBKT; i += 256) lcnt[i] = 0;
  __syncthreads();
  unsigned int rec[FCHUNK / 256];
  unsigned int meta[FCHUNK / 256];
#pragma unroll
  for (int j = 0; j < FCHUNK / 256; ++j) {
    int i = base + j * 256 + t;
    if (i < E) {
      int r = row[i], c = col[i];
      int b = c >> 7;
      rec[j] = (unsigned int)r | ((unsigned int)(c & 127) << 17);
      int lr = atomicAdd(&lcnt[b], 1);
      meta[j] = (unsigned int)lr | ((unsigned int)b << 16);
    } else {
      meta[j] = 0xFFFFFFFFu;
    }
  }
  __syncthreads();
  for (int i = t; i < NBKT; i += 256) {
    int c = lcnt[i];
    lbase[i] = c ? atomicAdd(&bcurs[i], c) : 0;
  }
  __syncthreads();
#pragma unroll
  for (int j = 0; j < FCHUNK / 256; ++j) {
    if (meta[j] != 0xFFFFFFFFu) {
      int b = meta[j] >> 16;
      int lr = meta[j] & 0xFFFF;
      recs[lbase[b] + lr] = rec[j];
    }
  }
}

// per-bucket degree -> dis = rsqrt(deg+1)
__global__ __launch_bounds__(256) void deg_dis_k(const unsigned int* __restrict__ recs,
                                                 const int* __restrict__ boffs,
                                                 float* __restrict__ dis, int N) {
  __shared__ int cnt[128];
  int b = blockIdx.x, t = threadIdx.x;
  if (t < 128) cnt[t] = 0;
  __syncthreads();
  int s = boffs[b], e = boffs[b + 1];
  for (int i = s + t; i < e; i += 256) atomicAdd(&cnt[recs[i] >> 17], 1);
  __syncthreads();
  if (t < 128) {
    int c = b * 128 + t;
    if (c < N) dis[c] = rsqrtf((float)(cnt[t] + 1));
  }
}

// ---------------- GEMM: G[node,:] = (X[node,:] @ W) * dis[node] ----------------
template <int K, int XS, int NOUT, int CH>
__global__ __launch_bounds__(256) void gemm_scale_k(const float* __restrict__ X,
                                                    const float* __restrict__ W,
                                                    const float* __restrict__ dis,
                                                    float* __restrict__ G, int n) {
  __shared__ float Xs[64 * XS];
  __shared__ float Ws[K * NOUT + 8];
  int t = threadIdx.x;
  int b0 = blockIdx.x * 64;
  for (int i = t; i < K * NOUT; i += 256) Ws[i] = W[i];
  int lim = n * K;
  for (int i = t; i < 64 * K; i += 256) {
    int r = i / K, c = i - r * K;
    int gi = b0 * K + i;
    Xs[r * XS + c] = (gi < lim) ? X[gi] : 0.f;
  }
  __syncthreads();
  int nl = t >> 2, ch = t & 3;
  float acc[CH];
#pragma unroll
  for (int j = 0; j < CH; ++j) acc[j] = 0.f;
  const float* xr = &Xs[nl * XS];
  const float* wc = &Ws[ch * CH];
  for (int k = 0; k < K; ++k) {
    float a = xr[k];
#pragma unroll
    for (int j = 0; j < CH; ++j) acc[j] = fmaf(a, wc[k * NOUT + j], acc[j]);
  }
  __syncthreads();
  int node = b0 + nl;
  float s = (node < n) ? dis[node] : 0.f;
  constexpr int ST = NOUT + 1;
#pragma unroll
  for (int j = 0; j < CH; ++j) {
    int jj = ch * CH + j;
    if (jj < NOUT) Xs[nl * ST + jj] = acc[j] * s;
  }
  __syncthreads();
  int gbase = b0 * NOUT;
  int glim = n * NOUT;
  for (int i = t; i < 64 * NOUT; i += 256) {
    int r = i / NOUT, c = i - r * NOUT;
    if (gbase + i < glim) G[gbase + i] = Xs[r * ST + c];
  }
}

// ---------------- bucket aggregation ----------------
// block = bucket: LDS acc[128][NOUT]; wave per record, lane = feature.
// out[c,:] = act(dis[c]*(sum_{r in N(c)} g[r,:] + g[c,:]) + b)   (g pre-scaled by dis[row])
template <int NOUT>
__global__ __launch_bounds__(256) void agg_bucket_k(const float* __restrict__ g,
                                                    const unsigned int* __restrict__ recs,
                                                    const int* __restrict__ boffs,
                                                    const float* __restrict__ dis,
                                                    const float* __restrict__ bias,
                                                    float* __restrict__ out, int N, int do_relu) {
  __shared__ float acc[128 * NOUT];
  int t = threadIdx.x;
  for (int i = t; i < 128 * NOUT; i += 256) acc[i] = 0.f;
  __syncthreads();
  int b = blockIdx.x;
  int s = boffs[b], e = boffs[b + 1];
  int wave = t >> 6, lane = t & 63;
  if (NOUT == 64 || lane < NOUT) {
    int i = s + wave;
    // 4 records in flight per wave for memory-level parallelism
    for (; i + 12 < e; i += 16) {
      unsigned int r0 = recs[i], r1 = recs[i + 4], r2 = recs[i + 8], r3 = recs[i + 12];
      float v0 = g[(r0 & 0x1FFFF) * NOUT + lane];
      float v1 = g[(r1 & 0x1FFFF) * NOUT + lane];
      float v2 = g[(r2 & 0x1FFFF) * NOUT + lane];
      float v3 = g[(r3 & 0x1FFFF) * NOUT + lane];
      atomicAdd(&acc[(r0 >> 17) * NOUT + lane], v0);
      atomicAdd(&acc[(r1 >> 17) * NOUT + lane], v1);
      atomicAdd(&acc[(r2 >> 17) * NOUT + lane], v2);
      atomicAdd(&acc[(r3 >> 17) * NOUT + lane], v3);
    }
    for (; i < e; i += 4) {
      unsigned int r = recs[i];
      float v = g[(r & 0x1FFFF) * NOUT + lane];
      atomicAdd(&acc[(r >> 17) * NOUT + lane], v);
    }
  }
  __syncthreads();
  int c0 = b * 128;
  for (int i = t; i < 128 * NOUT; i += 256) {
    int cl = i / NOUT, f = i - cl * NOUT;
    int c = c0 + cl;
    if (c < N) {
      float v = fmaf(dis[c], acc[i] + g[c * NOUT + f], bias[f]);
      out[c * NOUT + f] = do_relu ? fmaxf(v, 0.f) : v;
    }
  }
}

// ---------------- launch ----------------

extern "C" void kernel_launch(void* const* d_in, const int* in_sizes, int n_in,
                              void* d_out, int out_size, void* d_ws, size_t ws_size,
                              hipStream_t stream) {
  const float* x  = (const float*)d_in[0];
  const int*   ei = (const int*)d_in[1];
  const float* W1 = (const float*)d_in[2];
  const float* b1 = (const float*)d_in[3];
  const float* W2 = (const float*)d_in[4];
  const float* b2 = (const float*)d_in[5];
  const float* W3 = (const float*)d_in[6];
  const float* b3 = (const float*)d_in[7];
  const float* Wo = (const float*)d_in[8];
  const float* bo = (const float*)d_in[9];
  float* out = (float*)d_out;

  const int N = NODES;
  const int E = in_sizes[1] / 2;
  const int* rowp = ei;
  const int* colp = ei + E;

  char* p = (char*)d_ws;
  auto alloc = [&](size_t bytes) {
    void* r = (void*)p;
    p += (bytes + 255) & ~(size_t)255;
    return r;
  };
  int*   bcnt  = (int*)alloc((size_t)NBKT * 4);
  int*   bcurs = (int*)alloc((size_t)NBKT * 4);
  int*   boffs = (int*)alloc((size_t)(NBKT + 1) * 4);
  float* dis   = (float*)alloc((size_t)N * 4);
  unsigned int* recs = (unsigned int*)alloc((size_t)E * 4);
  float* bufA  = (float*)alloc((size_t)N * 64 * 4);
  float* bufB  = (float*)alloc((size_t)N * 64 * 4);

  zero_k<<<(NBKT + 255) / 256, 256, 0, stream>>>(bcnt, NBKT);
  bucket_hist_k<<<(E + HCHUNK - 1) / HCHUNK, 256, 0, stream>>>(colp, bcnt, E);
  bscan_k<<<1, 256, 0, stream>>>(bcnt, boffs, bcurs, NBKT, E);
  bucket_fill_k<<<(E + FCHUNK - 1) / FCHUNK, 256, 0, stream>>>(rowp, colp, bcurs, recs, E);
  deg_dis_k<<<NBKT, 256, 0, stream>>>(recs, boffs, dis, N);

  int gG = (N + 63) / 64;

  gemm_scale_k<100, 100, 64, 16><<<gG, 256, 0, stream>>>(x, W1, dis, bufA, N);
  agg_bucket_k<64><<<NBKT, 256, 0, stream>>>(bufA, recs, boffs, dis, b1, bufB, N, 1);

  gemm_scale_k<64, 65, 64, 16><<<gG, 256, 0, stream>>>(bufB, W2, dis, bufA, N);
  agg_bucket_k<64><<<NBKT, 256, 0, stream>>>(bufA, recs, boffs, dis, b2, bufB, N, 1);

  gemm_scale_k<64, 65, 64, 16><<<gG, 256, 0, stream>>>(bufB, W3, dis, bufA, N);
  agg_bucket_k<64><<<NBKT, 256, 0, stream>>>(bufA, recs, boffs, dis, b3, bufB, N, 1);

  gemm_scale_k<64, 65, 18, 5><<<gG, 256, 0, stream>>>(bufB, Wo, dis, bufA, N);
  agg_bucket_k<18><<<NBKT, 256, 0, stream>>>(bufA, recs, boffs, dis, bo, out, N, 0);
}

// Round 3
// 670.577 us; speedup vs baseline: 6.9334x; 6.9334x over previous
//
#include <hip/hip_runtime.h>

#define NODES 100000
#define NBKT 782            // ceil(100000/128) buckets of 128 cols
#define HCHUNK 8192         // edges per bucket_hist block
#define FCHUNK 4096         // edges per bucket_fill block (256 thr x 16)

// ---------------- small utils ----------------

__global__ __launch_bounds__(256) void zero_k(int* __restrict__ p, int n) {
  int i = blockIdx.x * 256 + threadIdx.x;
  if (i < n) p[i] = 0;
}

// ---------------- bucket build ----------------

__global__ __launch_bounds__(256) void bucket_hist_k(const int* __restrict__ col,
                                                     int* __restrict__ bcnt, int E) {
  __shared__ int h[NBKT];
  int t = threadIdx.x;
  for (int i = t; i < NBKT; i += 256) h[i] = 0;
  __syncthreads();
  int base = blockIdx.x * HCHUNK;
#pragma unroll 4
  for (int j = 0; j < HCHUNK / 256; ++j) {
    int i = base + j * 256 + t;
    if (i < E) atomicAdd(&h[col[i] >> 7], 1);
  }
  __syncthreads();
  for (int i = t; i < NBKT; i += 256) {
    int c = h[i];
    if (c) atomicAdd(&bcnt[i], c);
  }
}

// single-block exclusive scan over NBKT (<=1024) bucket counts -> offsets + cursors
__global__ __launch_bounds__(256) void bscan_k(const int* __restrict__ bcnt,
                                               int* __restrict__ boffs,
                                               int* __restrict__ bcurs, int nb, int E) {
  __shared__ int lds[256];
  int t = threadIdx.x;
  int base = t * 4;
  int v[4];
#pragma unroll
  for (int j = 0; j < 4; ++j) v[j] = (base + j < nb) ? bcnt[base + j] : 0;
  int s = v[0] + v[1] + v[2] + v[3];
  lds[t] = s;
  __syncthreads();
  for (int off = 1; off < 256; off <<= 1) {
    int y = (t >= off) ? lds[t - off] : 0;
    __syncthreads();
    lds[t] += y;
    __syncthreads();
  }
  int excl = lds[t] - s;
#pragma unroll
  for (int j = 0; j < 4; ++j) {
    int i = base + j;
    if (i < nb) { boffs[i] = excl; bcurs[i] = excl; }
    excl += v[j];
  }
  if (t == 255) boffs[nb] = E;
}

// scatter packed records (colLow<<17 | row) into bucket regions.
__global__ __launch_bounds__(256) void bucket_fill_k(const int* __restrict__ row,
                                                     const int* __restrict__ col,
                                                     int* __restrict__ bcurs,
                                                     unsigned int* __restrict__ recs, int E) {
  __shared__ int lcnt[NBKT];
  __shared__ int lbase[NBKT];
  int t = threadIdx.x;
  int base = blockIdx.x * FCHUNK;
  for (int i = t; i < NBKT; i += 256) lcnt[i] = 0;
  __syncthreads();
  unsigned int rec[FCHUNK / 256];
  unsigned int meta[FCHUNK / 256];
#pragma unroll
  for (int j = 0; j < FCHUNK / 256; ++j) {
    int i = base + j * 256 + t;
    if (i < E) {
      int r = row[i], c = col[i];
      int b = c >> 7;
      rec[j] = (unsigned int)r | ((unsigned int)(c & 127) << 17);
      int lr = atomicAdd(&lcnt[b], 1);
      meta[j] = (unsigned int)lr | ((unsigned int)b << 16);
    } else {
      meta[j] = 0xFFFFFFFFu;
    }
  }
  __syncthreads();
  for (int i = t; i < NBKT; i += 256) {
    int c = lcnt[i];
    lbase[i] = c ? atomicAdd(&bcurs[i], c) : 0;
  }
  __syncthreads();
#pragma unroll
  for (int j = 0; j < FCHUNK / 256; ++j) {
    if (meta[j] != 0xFFFFFFFFu) {
      int b = meta[j] >> 16;
      int lr = meta[j] & 0xFFFF;
      recs[lbase[b] + lr] = rec[j];
    }
  }
}

// records (bucketed by col) -> per-node CSR (offs, adj) + dis. One block per bucket;
// all writes stay inside this bucket's region => good write locality.
__global__ __launch_bounds__(256) void csr_k(const unsigned int* __restrict__ recs,
                                             const int* __restrict__ boffs,
                                             int* __restrict__ offs, int* __restrict__ adj,
                                             float* __restrict__ dis, int N, int E) {
  __shared__ int cnt[128];
  __shared__ int sa[128], sb[128];
  __shared__ int cur[128];
  int b = blockIdx.x, t = threadIdx.x;
  if (t < 128) cnt[t] = 0;
  __syncthreads();
  int s = boffs[b], e = boffs[b + 1];
  for (int i = s + t; i < e; i += 256) atomicAdd(&cnt[recs[i] >> 17], 1);
  __syncthreads();
  // inclusive scan over 128 counts (Hillis-Steele, double buffer)
  if (t < 128) sa[t] = cnt[t];
  __syncthreads();
#pragma unroll
  for (int off = 1; off < 128; off <<= 1) {
    if (t < 128) sb[t] = sa[t] + ((t >= off) ? sa[t - off] : 0);
    __syncthreads();
    if (t < 128) sa[t] = sb[t];
    __syncthreads();
  }
  if (t < 128) {
    int c = b * 128 + t;
    if (c < N) {
      int excl = sa[t] - cnt[t];
      offs[c] = s + excl;
      cur[t] = s + excl;
      dis[c] = rsqrtf((float)(cnt[t] + 1));  // +1 self loop
    }
  }
  if (b == 0 && t == 0) offs[N] = E;
  __syncthreads();
  for (int i = s + t; i < e; i += 256) {
    unsigned int r = recs[i];
    int p = atomicAdd(&cur[r >> 17], 1);
    adj[p] = (int)(r & 0x1FFFF);
  }
}

// ---------------- GEMM: G[node,:] = (X[node,:] @ W) * dis[node] ----------------
template <int K, int XS, int NOUT, int CH>
__global__ __launch_bounds__(256) void gemm_scale_k(const float* __restrict__ X,
                                                    const float* __restrict__ W,
                                                    const float* __restrict__ dis,
                                                    float* __restrict__ G, int n) {
  __shared__ float Xs[64 * XS];
  __shared__ float Ws[K * NOUT + 8];
  int t = threadIdx.x;
  int b0 = blockIdx.x * 64;
  for (int i = t; i < K * NOUT; i += 256) Ws[i] = W[i];
  int lim = n * K;
  for (int i = t; i < 64 * K; i += 256) {
    int r = i / K, c = i - r * K;
    int gi = b0 * K + i;
    Xs[r * XS + c] = (gi < lim) ? X[gi] : 0.f;
  }
  __syncthreads();
  int nl = t >> 2, ch = t & 3;
  float acc[CH];
#pragma unroll
  for (int j = 0; j < CH; ++j) acc[j] = 0.f;
  const float* xr = &Xs[nl * XS];
  const float* wc = &Ws[ch * CH];
  for (int k = 0; k < K; ++k) {
    float a = xr[k];
#pragma unroll
    for (int j = 0; j < CH; ++j) acc[j] = fmaf(a, wc[k * NOUT + j], acc[j]);
  }
  __syncthreads();
  int node = b0 + nl;
  float s = (node < n) ? dis[node] : 0.f;
  constexpr int ST = NOUT + 1;
#pragma unroll
  for (int j = 0; j < CH; ++j) {
    int jj = ch * CH + j;
    if (jj < NOUT) Xs[nl * ST + jj] = acc[j] * s;
  }
  __syncthreads();
  int gbase = b0 * NOUT;
  int glim = n * NOUT;
  for (int i = t; i < 64 * NOUT; i += 256) {
    int r = i / NOUT, c = i - r * NOUT;
    if (gbase + i < glim) G[gbase + i] = Xs[r * ST + c];
  }
}

// ---------------- aggregation: wave per node, lane = feature ----------------
// out[c,:] = act(dis[c]*(sum_{r in N(c)} g[r,:] + g[c,:]) + b)   (g pre-scaled by dis[row])
template <int NOUT>
__global__ __launch_bounds__(256) void agg_k(const float* __restrict__ g,
                                             const int* __restrict__ offs,
                                             const int* __restrict__ adj,
                                             const float* __restrict__ dis,
                                             const float* __restrict__ bias,
                                             float* __restrict__ out, int n, int do_relu) {
  int node = blockIdx.x * 4 + (threadIdx.x >> 6);
  int lane = threadIdx.x & 63;
  if (node >= n) return;
  if (NOUT < 64 && lane >= NOUT) return;
  float acc = g[node * NOUT + lane];  // self loop (g already scaled by dis[node])
  int s = offs[node], e = offs[node + 1];
  int i = s;
  // 8 gathers in flight
  for (; i + 8 <= e; i += 8) {
    int r0 = adj[i], r1 = adj[i + 1], r2 = adj[i + 2], r3 = adj[i + 3];
    int r4 = adj[i + 4], r5 = adj[i + 5], r6 = adj[i + 6], r7 = adj[i + 7];
    float a0 = g[r0 * NOUT + lane];
    float a1 = g[r1 * NOUT + lane];
    float a2 = g[r2 * NOUT + lane];
    float a3 = g[r3 * NOUT + lane];
    float a4 = g[r4 * NOUT + lane];
    float a5 = g[r5 * NOUT + lane];
    float a6 = g[r6 * NOUT + lane];
    float a7 = g[r7 * NOUT + lane];
    acc += ((a0 + a1) + (a2 + a3)) + ((a4 + a5) + (a6 + a7));
  }
  for (; i < e; ++i) acc += g[adj[i] * NOUT + lane];
  float v = fmaf(dis[node], acc, bias[lane]);
  out[node * NOUT + lane] = do_relu ? fmaxf(v, 0.f) : v;
}

// ---------------- launch ----------------

extern "C" void kernel_launch(void* const* d_in, const int* in_sizes, int n_in,
                              void* d_out, int out_size, void* d_ws, size_t ws_size,
                              hipStream_t stream) {
  const float* x  = (const float*)d_in[0];
  const int*   ei = (const int*)d_in[1];
  const float* W1 = (const float*)d_in[2];
  const float* b1 = (const float*)d_in[3];
  const float* W2 = (const float*)d_in[4];
  const float* b2 = (const float*)d_in[5];
  const float* W3 = (const float*)d_in[6];
  const float* b3 = (const float*)d_in[7];
  const float* Wo = (const float*)d_in[8];
  const float* bo = (const float*)d_in[9];
  float* out = (float*)d_out;

  const int N = NODES;
  const int E = in_sizes[1] / 2;
  const int* rowp = ei;
  const int* colp = ei + E;

  char* p = (char*)d_ws;
  auto alloc = [&](size_t bytes) {
    void* r = (void*)p;
    p += (bytes + 255) & ~(size_t)255;
    return r;
  };
  int*   bcnt  = (int*)alloc((size_t)NBKT * 4);
  int*   bcurs = (int*)alloc((size_t)NBKT * 4);
  int*   boffs = (int*)alloc((size_t)(NBKT + 1) * 4);
  float* dis   = (float*)alloc((size_t)N * 4);
  int*   offs  = (int*)alloc((size_t)(N + 1) * 4);
  int*   adj   = (int*)alloc((size_t)E * 4);
  // recs is dead after csr_k; alias it with bufA (gemm1 writes bufA after csr_k completes)
  unsigned int* recs = (unsigned int*)alloc((size_t)N * 64 * 4);  // E*4 <= N*64*4
  float* bufA  = (float*)recs;
  float* bufB  = (float*)alloc((size_t)N * 64 * 4);

  zero_k<<<(NBKT + 255) / 256, 256, 0, stream>>>(bcnt, NBKT);
  bucket_hist_k<<<(E + HCHUNK - 1) / HCHUNK, 256, 0, stream>>>(colp, bcnt, E);
  bscan_k<<<1, 256, 0, stream>>>(bcnt, boffs, bcurs, NBKT, E);
  bucket_fill_k<<<(E + FCHUNK - 1) / FCHUNK, 256, 0, stream>>>(rowp, colp, bcurs, recs, E);
  csr_k<<<NBKT, 256, 0, stream>>>(recs, boffs, offs, adj, dis, N, E);

  int gG = (N + 63) / 64;
  int gA = (N + 3) / 4;

  gemm_scale_k<100, 100, 64, 16><<<gG, 256, 0, stream>>>(x, W1, dis, bufA, N);
  agg_k<64><<<gA, 256, 0, stream>>>(bufA, offs, adj, dis, b1, bufB, N, 1);

  gemm_scale_k<64, 65, 64, 16><<<gG, 256, 0, stream>>>(bufB, W2, dis, bufA, N);
  agg_k<64><<<gA, 256, 0, stream>>>(bufA, offs, adj, dis, b2, bufB, N, 1);

  gemm_scale_k<64, 65, 64, 16><<<gG, 256, 0, stream>>>(bufB, W3, dis, bufA, N);
  agg_k<64><<<gA, 256, 0, stream>>>(bufA, offs, adj, dis, b3, bufB, N, 1);

  gemm_scale_k<64, 65, 18, 5><<<gG, 256, 0, stream>>>(bufB, Wo, dis, bufA, N);
  agg_k<18><<<gA, 256, 0, stream>>>(bufA, offs, adj, dis, bo, out, N, 0);
}

// Round 4
// 601.429 us; speedup vs baseline: 7.7305x; 1.1150x over previous
//
#include <hip/hip_runtime.h>

#define NODES 100000
#define NBKT 782            // ceil(100000/128) buckets of 128 cols
#define HCHUNK 8192         // edges per bucket_hist block
#define FCHUNK 4096         // edges per bucket_fill block (256 thr x 16)

typedef unsigned short u16;
typedef unsigned int u32;

__device__ __forceinline__ float bf2f(u16 u) {
  return __uint_as_float(((u32)u) << 16);
}
__device__ __forceinline__ u16 f2bf(float f) {  // RNE
  u32 x = __float_as_uint(f);
  return (u16)((x + 0x7FFFu + ((x >> 16) & 1u)) >> 16);
}

// ---------------- small utils ----------------

__global__ __launch_bounds__(256) void zero_k(int* __restrict__ p, int n) {
  int i = blockIdx.x * 256 + threadIdx.x;
  if (i < n) p[i] = 0;
}

// ---------------- bucket build ----------------

__global__ __launch_bounds__(256) void bucket_hist_k(const int* __restrict__ col,
                                                     int* __restrict__ bcnt, int E) {
  __shared__ int h[NBKT];
  int t = threadIdx.x;
  for (int i = t; i < NBKT; i += 256) h[i] = 0;
  __syncthreads();
  int base = blockIdx.x * HCHUNK;
#pragma unroll 4
  for (int j = 0; j < HCHUNK / 256; ++j) {
    int i = base + j * 256 + t;
    if (i < E) atomicAdd(&h[col[i] >> 7], 1);
  }
  __syncthreads();
  for (int i = t; i < NBKT; i += 256) {
    int c = h[i];
    if (c) atomicAdd(&bcnt[i], c);
  }
}

__global__ __launch_bounds__(256) void bscan_k(const int* __restrict__ bcnt,
                                               int* __restrict__ boffs,
                                               int* __restrict__ bcurs, int nb, int E) {
  __shared__ int lds[256];
  int t = threadIdx.x;
  int base = t * 4;
  int v[4];
#pragma unroll
  for (int j = 0; j < 4; ++j) v[j] = (base + j < nb) ? bcnt[base + j] : 0;
  int s = v[0] + v[1] + v[2] + v[3];
  lds[t] = s;
  __syncthreads();
  for (int off = 1; off < 256; off <<= 1) {
    int y = (t >= off) ? lds[t - off] : 0;
    __syncthreads();
    lds[t] += y;
    __syncthreads();
  }
  int excl = lds[t] - s;
#pragma unroll
  for (int j = 0; j < 4; ++j) {
    int i = base + j;
    if (i < nb) { boffs[i] = excl; bcurs[i] = excl; }
    excl += v[j];
  }
  if (t == 255) boffs[nb] = E;
}

// scatter packed records (colLow<<17 | row) into bucket regions.
__global__ __launch_bounds__(256) void bucket_fill_k(const int* __restrict__ row,
                                                     const int* __restrict__ col,
                                                     int* __restrict__ bcurs,
                                                     u32* __restrict__ recs, int E) {
  __shared__ int lcnt[NBKT];
  __shared__ int lbase[NBKT];
  int t = threadIdx.x;
  int base = blockIdx.x * FCHUNK;
  for (int i = t; i < NBKT; i += 256) lcnt[i] = 0;
  __syncthreads();
  u32 rec[FCHUNK / 256];
  u32 meta[FCHUNK / 256];
#pragma unroll
  for (int j = 0; j < FCHUNK / 256; ++j) {
    int i = base + j * 256 + t;
    if (i < E) {
      int r = row[i], c = col[i];
      int b = c >> 7;
      rec[j] = (u32)r | ((u32)(c & 127) << 17);
      int lr = atomicAdd(&lcnt[b], 1);
      meta[j] = (u32)lr | ((u32)b << 16);
    } else {
      meta[j] = 0xFFFFFFFFu;
    }
  }
  __syncthreads();
  for (int i = t; i < NBKT; i += 256) {
    int c = lcnt[i];
    lbase[i] = c ? atomicAdd(&bcurs[i], c) : 0;
  }
  __syncthreads();
#pragma unroll
  for (int j = 0; j < FCHUNK / 256; ++j) {
    if (meta[j] != 0xFFFFFFFFu) {
      int b = meta[j] >> 16;
      int lr = meta[j] & 0xFFFF;
      recs[lbase[b] + lr] = rec[j];
    }
  }
}

// records (bucketed by col) -> per-node CSR (offs, adj) + dis. One block per bucket.
__global__ __launch_bounds__(256) void csr_k(const u32* __restrict__ recs,
                                             const int* __restrict__ boffs,
                                             int* __restrict__ offs, int* __restrict__ adj,
                                             float* __restrict__ dis, int N, int E) {
  __shared__ int cnt[128];
  __shared__ int sa[128], sb[128];
  __shared__ int cur[128];
  int b = blockIdx.x, t = threadIdx.x;
  if (t < 128) cnt[t] = 0;
  __syncthreads();
  int s = boffs[b], e = boffs[b + 1];
  for (int i = s + t; i < e; i += 256) atomicAdd(&cnt[recs[i] >> 17], 1);
  __syncthreads();
  if (t < 128) sa[t] = cnt[t];
  __syncthreads();
#pragma unroll
  for (int off = 1; off < 128; off <<= 1) {
    if (t < 128) sb[t] = sa[t] + ((t >= off) ? sa[t - off] : 0);
    __syncthreads();
    if (t < 128) sa[t] = sb[t];
    __syncthreads();
  }
  if (t < 128) {
    int c = b * 128 + t;
    if (c < N) {
      int excl = sa[t] - cnt[t];
      offs[c] = s + excl;
      cur[t] = s + excl;
      dis[c] = rsqrtf((float)(cnt[t] + 1));  // +1 self loop
    }
  }
  if (b == 0 && t == 0) offs[N] = E;
  __syncthreads();
  for (int i = s + t; i < e; i += 256) {
    u32 r = recs[i];
    int p = atomicAdd(&cur[r >> 17], 1);
    adj[p] = (int)(r & 0x1FFFF);
  }
}

// ---------------- GEMM: G[node,:] = (X[node,:] @ W) * dis[node] ----------------
// BF16OUT: store G as bf16 (gather table for hidden layers), else fp32.
template <int K, int XS, int NOUT, int CH, int BF16OUT>
__global__ __launch_bounds__(256) void gemm_scale_k(const float* __restrict__ X,
                                                    const float* __restrict__ W,
                                                    const float* __restrict__ dis,
                                                    void* __restrict__ G, int n) {
  __shared__ float Xs[64 * XS];
  __shared__ float Ws[K * NOUT + 8];
  int t = threadIdx.x;
  int b0 = blockIdx.x * 64;
  for (int i = t; i < K * NOUT; i += 256) Ws[i] = W[i];
  int lim = n * K;
  for (int i = t; i < 64 * K; i += 256) {
    int r = i / K, c = i - r * K;
    int gi = b0 * K + i;
    Xs[r * XS + c] = (gi < lim) ? X[gi] : 0.f;
  }
  __syncthreads();
  int nl = t >> 2, ch = t & 3;
  float acc[CH];
#pragma unroll
  for (int j = 0; j < CH; ++j) acc[j] = 0.f;
  const float* xr = &Xs[nl * XS];
  const float* wc = &Ws[ch * CH];
  for (int k = 0; k < K; ++k) {
    float a = xr[k];
#pragma unroll
    for (int j = 0; j < CH; ++j) acc[j] = fmaf(a, wc[k * NOUT + j], acc[j]);
  }
  __syncthreads();
  int node = b0 + nl;
  float s = (node < n) ? dis[node] : 0.f;
  constexpr int ST = NOUT + 1;
#pragma unroll
  for (int j = 0; j < CH; ++j) {
    int jj = ch * CH + j;
    if (jj < NOUT) Xs[nl * ST + jj] = acc[j] * s;
  }
  __syncthreads();
  int gbase = b0 * NOUT;
  int glim = n * NOUT;
  for (int i = t; i < 64 * NOUT; i += 256) {
    int r = i / NOUT, c = i - r * NOUT;
    if (gbase + i < glim) {
      float v = Xs[r * ST + c];
      if (BF16OUT) ((u16*)G)[gbase + i] = f2bf(v);
      else         ((float*)G)[gbase + i] = v;
    }
  }
}

// ---------------- aggregation ----------------
// hidden layers: bf16 gather table, fp32 accumulate, ReLU, fp32 h out.
// wave per node, lane = feature (64). Row = 128B contiguous.
__global__ __launch_bounds__(256) void agg_bf16_k(const u16* __restrict__ g,
                                                  const int* __restrict__ offs,
                                                  const int* __restrict__ adj,
                                                  const float* __restrict__ dis,
                                                  const float* __restrict__ bias,
                                                  float* __restrict__ out, int n) {
  int node = blockIdx.x * 4 + (threadIdx.x >> 6);
  int lane = threadIdx.x & 63;
  if (node >= n) return;
  float acc = bf2f(g[node * 64 + lane]);  // self loop (g pre-scaled by dis[node])
  int s = offs[node], e = offs[node + 1];
  int i = s;
  for (; i + 8 <= e; i += 8) {
    int r0 = adj[i], r1 = adj[i + 1], r2 = adj[i + 2], r3 = adj[i + 3];
    int r4 = adj[i + 4], r5 = adj[i + 5], r6 = adj[i + 6], r7 = adj[i + 7];
    u16 a0 = g[r0 * 64 + lane];
    u16 a1 = g[r1 * 64 + lane];
    u16 a2 = g[r2 * 64 + lane];
    u16 a3 = g[r3 * 64 + lane];
    u16 a4 = g[r4 * 64 + lane];
    u16 a5 = g[r5 * 64 + lane];
    u16 a6 = g[r6 * 64 + lane];
    u16 a7 = g[r7 * 64 + lane];
    acc += ((bf2f(a0) + bf2f(a1)) + (bf2f(a2) + bf2f(a3))) +
           ((bf2f(a4) + bf2f(a5)) + (bf2f(a6) + bf2f(a7)));
  }
  for (; i < e; ++i) acc += bf2f(g[adj[i] * 64 + lane]);
  float v = fmaf(dis[node], acc, bias[lane]);
  out[node * 64 + lane] = fmaxf(v, 0.f);
}

// final layer: fp32 gather, no relu
template <int NOUT>
__global__ __launch_bounds__(256) void agg_k(const float* __restrict__ g,
                                             const int* __restrict__ offs,
                                             const int* __restrict__ adj,
                                             const float* __restrict__ dis,
                                             const float* __restrict__ bias,
                                             float* __restrict__ out, int n, int do_relu) {
  int node = blockIdx.x * 4 + (threadIdx.x >> 6);
  int lane = threadIdx.x & 63;
  if (node >= n) return;
  if (NOUT < 64 && lane >= NOUT) return;
  float acc = g[node * NOUT + lane];
  int s = offs[node], e = offs[node + 1];
  int i = s;
  for (; i + 8 <= e; i += 8) {
    int r0 = adj[i], r1 = adj[i + 1], r2 = adj[i + 2], r3 = adj[i + 3];
    int r4 = adj[i + 4], r5 = adj[i + 5], r6 = adj[i + 6], r7 = adj[i + 7];
    float a0 = g[r0 * NOUT + lane];
    float a1 = g[r1 * NOUT + lane];
    float a2 = g[r2 * NOUT + lane];
    float a3 = g[r3 * NOUT + lane];
    float a4 = g[r4 * NOUT + lane];
    float a5 = g[r5 * NOUT + lane];
    float a6 = g[r6 * NOUT + lane];
    float a7 = g[r7 * NOUT + lane];
    acc += ((a0 + a1) + (a2 + a3)) + ((a4 + a5) + (a6 + a7));
  }
  for (; i < e; ++i) acc += g[adj[i] * NOUT + lane];
  float v = fmaf(dis[node], acc, bias[lane]);
  out[node * NOUT + lane] = do_relu ? fmaxf(v, 0.f) : v;
}

// ---------------- launch ----------------

extern "C" void kernel_launch(void* const* d_in, const int* in_sizes, int n_in,
                              void* d_out, int out_size, void* d_ws, size_t ws_size,
                              hipStream_t stream) {
  const float* x  = (const float*)d_in[0];
  const int*   ei = (const int*)d_in[1];
  const float* W1 = (const float*)d_in[2];
  const float* b1 = (const float*)d_in[3];
  const float* W2 = (const float*)d_in[4];
  const float* b2 = (const float*)d_in[5];
  const float* W3 = (const float*)d_in[6];
  const float* b3 = (const float*)d_in[7];
  const float* Wo = (const float*)d_in[8];
  const float* bo = (const float*)d_in[9];
  float* out = (float*)d_out;

  const int N = NODES;
  const int E = in_sizes[1] / 2;
  const int* rowp = ei;
  const int* colp = ei + E;

  char* p = (char*)d_ws;
  auto alloc = [&](size_t bytes) {
    void* r = (void*)p;
    p += (bytes + 255) & ~(size_t)255;
    return r;
  };
  int*   bcnt  = (int*)alloc((size_t)NBKT * 4);
  int*   bcurs = (int*)alloc((size_t)NBKT * 4);
  int*   boffs = (int*)alloc((size_t)(NBKT + 1) * 4);
  float* dis   = (float*)alloc((size_t)N * 4);
  int*   offs  = (int*)alloc((size_t)(N + 1) * 4);
  int*   adj   = (int*)alloc((size_t)E * 4);
  // recs (E*4 = 12.8MB) is dead after csr_k; alias with the bf16 gather table (N*64*2 = 12.8MB)
  u32*   recs  = (u32*)alloc((size_t)N * 64 * 2);
  u16*   gb    = (u16*)recs;
  float* h     = (float*)alloc((size_t)N * 64 * 4);   // fp32 hidden activations
  float* g4    = (float*)alloc((size_t)N * 18 * 4);   // fp32 gather table, final layer

  zero_k<<<(NBKT + 255) / 256, 256, 0, stream>>>(bcnt, NBKT);
  bucket_hist_k<<<(E + HCHUNK - 1) / HCHUNK, 256, 0, stream>>>(colp, bcnt, E);
  bscan_k<<<1, 256, 0, stream>>>(bcnt, boffs, bcurs, NBKT, E);
  bucket_fill_k<<<(E + FCHUNK - 1) / FCHUNK, 256, 0, stream>>>(rowp, colp, bcurs, recs, E);
  csr_k<<<NBKT, 256, 0, stream>>>(recs, boffs, offs, adj, dis, N, E);

  int gG = (N + 63) / 64;
  int gA = (N + 3) / 4;

  gemm_scale_k<100, 100, 64, 16, 1><<<gG, 256, 0, stream>>>(x, W1, dis, gb, N);
  agg_bf16_k<<<gA, 256, 0, stream>>>(gb, offs, adj, dis, b1, h, N);

  gemm_scale_k<64, 65, 64, 16, 1><<<gG, 256, 0, stream>>>(h, W2, dis, gb, N);
  agg_bf16_k<<<gA, 256, 0, stream>>>(gb, offs, adj, dis, b2, h, N);

  gemm_scale_k<64, 65, 64, 16, 1><<<gG, 256, 0, stream>>>(h, W3, dis, gb, N);
  agg_bf16_k<<<gA, 256, 0, stream>>>(gb, offs, adj, dis, b3, h, N);

  gemm_scale_k<64, 65, 18, 5, 0><<<gG, 256, 0, stream>>>(h, Wo, dis, g4, N);
  agg_k<18><<<gA, 256, 0, stream>>>(g4, offs, adj, dis, bo, out, N, 0);
}

// Round 5
// 541.987 us; speedup vs baseline: 8.5784x; 1.1097x over previous
//
#include <hip/hip_runtime.h>

#define NODES 100000
#define NBKT 782            // ceil(100000/128) buckets of 128 cols
#define HCHUNK 8192         // edges per bucket_hist block
#define FCHUNK 4096         // edges per bucket_fill block (256 thr x 16)

typedef unsigned short u16;
typedef unsigned int u32;

__device__ __forceinline__ float bflo(u32 v) { return __uint_as_float(v << 16); }
__device__ __forceinline__ float bfhi(u32 v) { return __uint_as_float(v & 0xFFFF0000u); }
__device__ __forceinline__ u16 f2bf(float f) {  // RNE
  u32 x = __float_as_uint(f);
  return (u16)((x + 0x7FFFu + ((x >> 16) & 1u)) >> 16);
}

// ---------------- small utils ----------------

__global__ __launch_bounds__(256) void zero_k(int* __restrict__ p, int n) {
  int i = blockIdx.x * 256 + threadIdx.x;
  if (i < n) p[i] = 0;
}

// ---------------- bucket build ----------------

__global__ __launch_bounds__(256) void bucket_hist_k(const int* __restrict__ col,
                                                     int* __restrict__ bcnt, int E) {
  __shared__ int h[NBKT];
  int t = threadIdx.x;
  for (int i = t; i < NBKT; i += 256) h[i] = 0;
  __syncthreads();
  int base = blockIdx.x * HCHUNK;
#pragma unroll 4
  for (int j = 0; j < HCHUNK / 256; ++j) {
    int i = base + j * 256 + t;
    if (i < E) atomicAdd(&h[col[i] >> 7], 1);
  }
  __syncthreads();
  for (int i = t; i < NBKT; i += 256) {
    int c = h[i];
    if (c) atomicAdd(&bcnt[i], c);
  }
}

__global__ __launch_bounds__(256) void bscan_k(const int* __restrict__ bcnt,
                                               int* __restrict__ boffs,
                                               int* __restrict__ bcurs, int nb, int E) {
  __shared__ int lds[256];
  int t = threadIdx.x;
  int base = t * 4;
  int v[4];
#pragma unroll
  for (int j = 0; j < 4; ++j) v[j] = (base + j < nb) ? bcnt[base + j] : 0;
  int s = v[0] + v[1] + v[2] + v[3];
  lds[t] = s;
  __syncthreads();
  for (int off = 1; off < 256; off <<= 1) {
    int y = (t >= off) ? lds[t - off] : 0;
    __syncthreads();
    lds[t] += y;
    __syncthreads();
  }
  int excl = lds[t] - s;
#pragma unroll
  for (int j = 0; j < 4; ++j) {
    int i = base + j;
    if (i < nb) { boffs[i] = excl; bcurs[i] = excl; }
    excl += v[j];
  }
  if (t == 255) boffs[nb] = E;
}

// scatter packed records (colLow<<17 | row) into bucket regions.
__global__ __launch_bounds__(256) void bucket_fill_k(const int* __restrict__ row,
                                                     const int* __restrict__ col,
                                                     int* __restrict__ bcurs,
                                                     u32* __restrict__ recs, int E) {
  __shared__ int lcnt[NBKT];
  __shared__ int lbase[NBKT];
  int t = threadIdx.x;
  int base = blockIdx.x * FCHUNK;
  for (int i = t; i < NBKT; i += 256) lcnt[i] = 0;
  __syncthreads();
  u32 rec[FCHUNK / 256];
  u32 meta[FCHUNK / 256];
#pragma unroll
  for (int j = 0; j < FCHUNK / 256; ++j) {
    int i = base + j * 256 + t;
    if (i < E) {
      int r = row[i], c = col[i];
      int b = c >> 7;
      rec[j] = (u32)r | ((u32)(c & 127) << 17);
      int lr = atomicAdd(&lcnt[b], 1);
      meta[j] = (u32)lr | ((u32)b << 16);
    } else {
      meta[j] = 0xFFFFFFFFu;
    }
  }
  __syncthreads();
  for (int i = t; i < NBKT; i += 256) {
    int c = lcnt[i];
    lbase[i] = c ? atomicAdd(&bcurs[i], c) : 0;
  }
  __syncthreads();
#pragma unroll
  for (int j = 0; j < FCHUNK / 256; ++j) {
    if (meta[j] != 0xFFFFFFFFu) {
      int b = meta[j] >> 16;
      int lr = meta[j] & 0xFFFF;
      recs[lbase[b] + lr] = rec[j];
    }
  }
}

// records (bucketed by col) -> per-node CSR (offs, adj) + dis. One block per bucket.
__global__ __launch_bounds__(256) void csr_k(const u32* __restrict__ recs,
                                             const int* __restrict__ boffs,
                                             int* __restrict__ offs, int* __restrict__ adj,
                                             float* __restrict__ dis, int N, int E) {
  __shared__ int cnt[128];
  __shared__ int sa[128], sb[128];
  __shared__ int cur[128];
  int b = blockIdx.x, t = threadIdx.x;
  if (t < 128) cnt[t] = 0;
  __syncthreads();
  int s = boffs[b], e = boffs[b + 1];
  for (int i = s + t; i < e; i += 256) atomicAdd(&cnt[recs[i] >> 17], 1);
  __syncthreads();
  if (t < 128) sa[t] = cnt[t];
  __syncthreads();
#pragma unroll
  for (int off = 1; off < 128; off <<= 1) {
    if (t < 128) sb[t] = sa[t] + ((t >= off) ? sa[t - off] : 0);
    __syncthreads();
    if (t < 128) sa[t] = sb[t];
    __syncthreads();
  }
  if (t < 128) {
    int c = b * 128 + t;
    if (c < N) {
      int excl = sa[t] - cnt[t];
      offs[c] = s + excl;
      cur[t] = s + excl;
      dis[c] = rsqrtf((float)(cnt[t] + 1));  // +1 self loop
    }
  }
  if (b == 0 && t == 0) offs[N] = E;
  __syncthreads();
  for (int i = s + t; i < e; i += 256) {
    u32 r = recs[i];
    int p = atomicAdd(&cur[r >> 17], 1);
    adj[p] = (int)(r & 0x1FFFF);
  }
}

// ---------------- GEMM: G[node,:] = (X[node,:] @ W) * dis[node] ----------------
template <int K, int XS, int NOUT, int CH, int BF16OUT>
__global__ __launch_bounds__(256) void gemm_scale_k(const float* __restrict__ X,
                                                    const float* __restrict__ W,
                                                    const float* __restrict__ dis,
                                                    void* __restrict__ G, int n) {
  __shared__ float Xs[64 * XS];
  __shared__ float Ws[K * NOUT + 8];
  int t = threadIdx.x;
  int b0 = blockIdx.x * 64;
  for (int i = t; i < K * NOUT; i += 256) Ws[i] = W[i];
  int lim = n * K;
  for (int i = t; i < 64 * K; i += 256) {
    int r = i / K, c = i - r * K;
    int gi = b0 * K + i;
    Xs[r * XS + c] = (gi < lim) ? X[gi] : 0.f;
  }
  __syncthreads();
  int nl = t >> 2, ch = t & 3;
  float acc[CH];
#pragma unroll
  for (int j = 0; j < CH; ++j) acc[j] = 0.f;
  const float* xr = &Xs[nl * XS];
  const float* wc = &Ws[ch * CH];
  for (int k = 0; k < K; ++k) {
    float a = xr[k];
#pragma unroll
    for (int j = 0; j < CH; ++j) acc[j] = fmaf(a, wc[k * NOUT + j], acc[j]);
  }
  __syncthreads();
  int node = b0 + nl;
  float s = (node < n) ? dis[node] : 0.f;
  constexpr int ST = NOUT + 1;
#pragma unroll
  for (int j = 0; j < CH; ++j) {
    int jj = ch * CH + j;
    if (jj < NOUT) Xs[nl * ST + jj] = acc[j] * s;
  }
  __syncthreads();
  int gbase = b0 * NOUT;
  int glim = n * NOUT;
  for (int i = t; i < 64 * NOUT; i += 256) {
    int r = i / NOUT, c = i - r * NOUT;
    if (gbase + i < glim) {
      float v = Xs[r * ST + c];
      if (BF16OUT) ((u16*)G)[gbase + i] = f2bf(v);
      else         ((float*)G)[gbase + i] = v;
    }
  }
}

// ---------------- aggregation (hidden): 2 edges per wave-gather ----------------
// wave = 2 halves of 32 lanes; half h owns edge i+h; lane loads u32 = 2 bf16 feats.
// combine halves with shfl_xor(32); self loop + bias + relu post-combine.
__global__ __launch_bounds__(256) void agg_bf16_k(const u16* __restrict__ g,
                                                  const int* __restrict__ offs,
                                                  const int* __restrict__ adj,
                                                  const float* __restrict__ dis,
                                                  const float* __restrict__ bias,
                                                  float* __restrict__ out, int n) {
  int node = blockIdx.x * 4 + (threadIdx.x >> 6);
  int lane = threadIdx.x & 63;
  int half = lane >> 5, fl = lane & 31;
  if (node >= n) return;
  const u32* g32 = (const u32*)g;
  float acc0 = 0.f, acc1 = 0.f;
  int s = offs[node], e = offs[node + 1];
  int i = s;
  for (; i + 8 <= e; i += 8) {  // 4 pairs in flight
    int r0 = adj[i + half];
    int r1 = adj[i + 2 + half];
    int r2 = adj[i + 4 + half];
    int r3 = adj[i + 6 + half];
    u32 v0 = g32[(r0 << 5) + fl];
    u32 v1 = g32[(r1 << 5) + fl];
    u32 v2 = g32[(r2 << 5) + fl];
    u32 v3 = g32[(r3 << 5) + fl];
    acc0 += (bflo(v0) + bflo(v1)) + (bflo(v2) + bflo(v3));
    acc1 += (bfhi(v0) + bfhi(v1)) + (bfhi(v2) + bfhi(v3));
  }
  for (; i + 2 <= e; i += 2) {
    int r = adj[i + half];
    u32 v = g32[(r << 5) + fl];
    acc0 += bflo(v);
    acc1 += bfhi(v);
  }
  if (i < e) {  // odd tail edge: only half 0 counts it
    int r = adj[i];
    u32 v = g32[(r << 5) + fl];
    if (half == 0) { acc0 += bflo(v); acc1 += bfhi(v); }
  }
  // combine even/odd halves (same features, different edge subsets)
  acc0 += __shfl_xor(acc0, 32, 64);
  acc1 += __shfl_xor(acc1, 32, 64);
  // self loop (g pre-scaled by dis[node])
  u32 vs = g32[(node << 5) + fl];
  acc0 += bflo(vs);
  acc1 += bfhi(vs);
  float d = dis[node];
  float o0 = fmaxf(fmaf(d, acc0, bias[2 * fl]), 0.f);
  float o1 = fmaxf(fmaf(d, acc1, bias[2 * fl + 1]), 0.f);
  if (half == 0) {
    float2 st = {o0, o1};
    *(float2*)(out + node * 64 + 2 * fl) = st;
  }
}

// ---------------- aggregation (final, 18-wide fp32): 2 edges per wave-gather ----------------
__global__ __launch_bounds__(256) void agg_f18_k(const float* __restrict__ g,
                                                 const int* __restrict__ offs,
                                                 const int* __restrict__ adj,
                                                 const float* __restrict__ dis,
                                                 const float* __restrict__ bias,
                                                 float* __restrict__ out, int n) {
  int node = blockIdx.x * 4 + (threadIdx.x >> 6);
  int lane = threadIdx.x & 63;
  int half = lane >> 5, fl = lane & 31;
  if (node >= n) return;
  bool act = fl < 18;
  float acc = 0.f;
  int s = offs[node], e = offs[node + 1];
  int i = s;
  if (act) {
    for (; i + 8 <= e; i += 8) {
      int r0 = adj[i + half];
      int r1 = adj[i + 2 + half];
      int r2 = adj[i + 4 + half];
      int r3 = adj[i + 6 + half];
      float a0 = g[r0 * 18 + fl];
      float a1 = g[r1 * 18 + fl];
      float a2 = g[r2 * 18 + fl];
      float a3 = g[r3 * 18 + fl];
      acc += (a0 + a1) + (a2 + a3);
    }
    for (; i + 2 <= e; i += 2) acc += g[adj[i + half] * 18 + fl];
    if (i < e && half == 0) acc += g[adj[i] * 18 + fl];
  }
  acc += __shfl_xor(acc, 32, 64);  // all 64 lanes participate
  if (act) {
    acc += g[node * 18 + fl];  // self loop
    float v = fmaf(dis[node], acc, bias[fl]);
    if (half == 0) out[node * 18 + fl] = v;
  }
}

// ---------------- launch ----------------

extern "C" void kernel_launch(void* const* d_in, const int* in_sizes, int n_in,
                              void* d_out, int out_size, void* d_ws, size_t ws_size,
                              hipStream_t stream) {
  const float* x  = (const float*)d_in[0];
  const int*   ei = (const int*)d_in[1];
  const float* W1 = (const float*)d_in[2];
  const float* b1 = (const float*)d_in[3];
  const float* W2 = (const float*)d_in[4];
  const float* b2 = (const float*)d_in[5];
  const float* W3 = (const float*)d_in[6];
  const float* b3 = (const float*)d_in[7];
  const float* Wo = (const float*)d_in[8];
  const float* bo = (const float*)d_in[9];
  float* out = (float*)d_out;

  const int N = NODES;
  const int E = in_sizes[1] / 2;
  const int* rowp = ei;
  const int* colp = ei + E;

  char* p = (char*)d_ws;
  auto alloc = [&](size_t bytes) {
    void* r = (void*)p;
    p += (bytes + 255) & ~(size_t)255;
    return r;
  };
  int*   bcnt  = (int*)alloc((size_t)NBKT * 4);
  int*   bcurs = (int*)alloc((size_t)NBKT * 4);
  int*   boffs = (int*)alloc((size_t)(NBKT + 1) * 4);
  float* dis   = (float*)alloc((size_t)N * 4);
  int*   offs  = (int*)alloc((size_t)(N + 1) * 4);
  int*   adj   = (int*)alloc((size_t)E * 4);
  // recs (E*4 = 12.8MB) dead after csr_k; alias with bf16 gather table (N*64*2 = 12.8MB)
  u32*   recs  = (u32*)alloc((size_t)N * 64 * 2);
  u16*   gb    = (u16*)recs;
  float* h     = (float*)alloc((size_t)N * 64 * 4);   // fp32 hidden activations
  float* g4    = (float*)alloc((size_t)N * 18 * 4);   // fp32 gather table, final layer

  zero_k<<<(NBKT + 255) / 256, 256, 0, stream>>>(bcnt, NBKT);
  bucket_hist_k<<<(E + HCHUNK - 1) / HCHUNK, 256, 0, stream>>>(colp, bcnt, E);
  bscan_k<<<1, 256, 0, stream>>>(bcnt, boffs, bcurs, NBKT, E);
  bucket_fill_k<<<(E + FCHUNK - 1) / FCHUNK, 256, 0, stream>>>(rowp, colp, bcurs, recs, E);
  csr_k<<<NBKT, 256, 0, stream>>>(recs, boffs, offs, adj, dis, N, E);

  int gG = (N + 63) / 64;
  int gA = (N + 3) / 4;

  gemm_scale_k<100, 100, 64, 16, 1><<<gG, 256, 0, stream>>>(x, W1, dis, gb, N);
  agg_bf16_k<<<gA, 256, 0, stream>>>(gb, offs, adj, dis, b1, h, N);

  gemm_scale_k<64, 65, 64, 16, 1><<<gG, 256, 0, stream>>>(h, W2, dis, gb, N);
  agg_bf16_k<<<gA, 256, 0, stream>>>(gb, offs, adj, dis, b2, h, N);

  gemm_scale_k<64, 65, 64, 16, 1><<<gG, 256, 0, stream>>>(h, W3, dis, gb, N);
  agg_bf16_k<<<gA, 256, 0, stream>>>(gb, offs, adj, dis, b3, h, N);

  gemm_scale_k<64, 65, 18, 5, 0><<<gG, 256, 0, stream>>>(h, Wo, dis, g4, N);
  agg_f18_k<<<gA, 256, 0, stream>>>(g4, offs, adj, dis, bo, out, N);
}

// Round 6
// 494.539 us; speedup vs baseline: 9.4014x; 1.0959x over previous
//
#include <hip/hip_runtime.h>
#include <hip/hip_fp16.h>

#define NODES 100000
#define NBKT 782            // ceil(100000/128) buckets of 128 cols
#define HCHUNK 8192         // edges per bucket_hist block
#define FCHUNK 4096         // edges per bucket_fill block (256 thr x 16)

typedef unsigned short u16;
typedef unsigned int u32;

__device__ __forceinline__ float bflo(u32 v) { return __uint_as_float(v << 16); }
__device__ __forceinline__ float bfhi(u32 v) { return __uint_as_float(v & 0xFFFF0000u); }
__device__ __forceinline__ u16 f2bf(float f) {  // RNE
  u32 x = __float_as_uint(f);
  return (u16)((x + 0x7FFFu + ((x >> 16) & 1u)) >> 16);
}

// ---------------- small utils ----------------

__global__ __launch_bounds__(256) void zero_k(int* __restrict__ p, int n) {
  int i = blockIdx.x * 256 + threadIdx.x;
  if (i < n) p[i] = 0;
}

// ---------------- bucket build ----------------

__global__ __launch_bounds__(256) void bucket_hist_k(const int* __restrict__ col,
                                                     int* __restrict__ bcnt, int E) {
  __shared__ int h[NBKT];
  int t = threadIdx.x;
  for (int i = t; i < NBKT; i += 256) h[i] = 0;
  __syncthreads();
  int base = blockIdx.x * HCHUNK;
#pragma unroll 4
  for (int j = 0; j < HCHUNK / 256; ++j) {
    int i = base + j * 256 + t;
    if (i < E) atomicAdd(&h[col[i] >> 7], 1);
  }
  __syncthreads();
  for (int i = t; i < NBKT; i += 256) {
    int c = h[i];
    if (c) atomicAdd(&bcnt[i], c);
  }
}

__global__ __launch_bounds__(256) void bscan_k(const int* __restrict__ bcnt,
                                               int* __restrict__ boffs,
                                               int* __restrict__ bcurs, int nb, int E) {
  __shared__ int lds[256];
  int t = threadIdx.x;
  int base = t * 4;
  int v[4];
#pragma unroll
  for (int j = 0; j < 4; ++j) v[j] = (base + j < nb) ? bcnt[base + j] : 0;
  int s = v[0] + v[1] + v[2] + v[3];
  lds[t] = s;
  __syncthreads();
  for (int off = 1; off < 256; off <<= 1) {
    int y = (t >= off) ? lds[t - off] : 0;
    __syncthreads();
    lds[t] += y;
    __syncthreads();
  }
  int excl = lds[t] - s;
#pragma unroll
  for (int j = 0; j < 4; ++j) {
    int i = base + j;
    if (i < nb) { boffs[i] = excl; bcurs[i] = excl; }
    excl += v[j];
  }
  if (t == 255) boffs[nb] = E;
}

// scatter packed records (colLow<<17 | row) into bucket regions.
__global__ __launch_bounds__(256) void bucket_fill_k(const int* __restrict__ row,
                                                     const int* __restrict__ col,
                                                     int* __restrict__ bcurs,
                                                     u32* __restrict__ recs, int E) {
  __shared__ int lcnt[NBKT];
  __shared__ int lbase[NBKT];
  int t = threadIdx.x;
  int base = blockIdx.x * FCHUNK;
  for (int i = t; i < NBKT; i += 256) lcnt[i] = 0;
  __syncthreads();
  u32 rec[FCHUNK / 256];
  u32 meta[FCHUNK / 256];
#pragma unroll
  for (int j = 0; j < FCHUNK / 256; ++j) {
    int i = base + j * 256 + t;
    if (i < E) {
      int r = row[i], c = col[i];
      int b = c >> 7;
      rec[j] = (u32)r | ((u32)(c & 127) << 17);
      int lr = atomicAdd(&lcnt[b], 1);
      meta[j] = (u32)lr | ((u32)b << 16);
    } else {
      meta[j] = 0xFFFFFFFFu;
    }
  }
  __syncthreads();
  for (int i = t; i < NBKT; i += 256) {
    int c = lcnt[i];
    lbase[i] = c ? atomicAdd(&bcurs[i], c) : 0;
  }
  __syncthreads();
#pragma unroll
  for (int j = 0; j < FCHUNK / 256; ++j) {
    if (meta[j] != 0xFFFFFFFFu) {
      int b = meta[j] >> 16;
      int lr = meta[j] & 0xFFFF;
      recs[lbase[b] + lr] = rec[j];
    }
  }
}

// records (bucketed by col) -> per-node CSR (offs, adj) + dis. One block per bucket.
__global__ __launch_bounds__(256) void csr_k(const u32* __restrict__ recs,
                                             const int* __restrict__ boffs,
                                             int* __restrict__ offs, int* __restrict__ adj,
                                             float* __restrict__ dis, int N, int E) {
  __shared__ int cnt[128];
  __shared__ int sa[128], sb[128];
  __shared__ int cur[128];
  int b = blockIdx.x, t = threadIdx.x;
  if (t < 128) cnt[t] = 0;
  __syncthreads();
  int s = boffs[b], e = boffs[b + 1];
  for (int i = s + t; i < e; i += 256) atomicAdd(&cnt[recs[i] >> 17], 1);
  __syncthreads();
  if (t < 128) sa[t] = cnt[t];
  __syncthreads();
#pragma unroll
  for (int off = 1; off < 128; off <<= 1) {
    if (t < 128) sb[t] = sa[t] + ((t >= off) ? sa[t - off] : 0);
    __syncthreads();
    if (t < 128) sa[t] = sb[t];
    __syncthreads();
  }
  if (t < 128) {
    int c = b * 128 + t;
    if (c < N) {
      int excl = sa[t] - cnt[t];
      offs[c] = s + excl;
      cur[t] = s + excl;
      dis[c] = rsqrtf((float)(cnt[t] + 1));  // +1 self loop
    }
  }
  if (b == 0 && t == 0) offs[N] = E;
  __syncthreads();
  for (int i = s + t; i < e; i += 256) {
    u32 r = recs[i];
    int p = atomicAdd(&cur[r >> 17], 1);
    adj[p] = (int)(r & 0x1FFFF);
  }
}

// ---------------- GEMM: G[node,:] = (X[node,:] @ W) * dis[node] ----------------
// OUTFMT: 0 = fp32, 1 = bf16, 2 = fp16
template <int K, int XS, int NOUT, int CH, int OUTFMT>
__global__ __launch_bounds__(256) void gemm_scale_k(const float* __restrict__ X,
                                                    const float* __restrict__ W,
                                                    const float* __restrict__ dis,
                                                    void* __restrict__ G, int n) {
  __shared__ float Xs[64 * XS];
  __shared__ float Ws[K * NOUT + 8];
  int t = threadIdx.x;
  int b0 = blockIdx.x * 64;
  for (int i = t; i < K * NOUT; i += 256) Ws[i] = W[i];
  int lim = n * K;
  for (int i = t; i < 64 * K; i += 256) {
    int r = i / K, c = i - r * K;
    int gi = b0 * K + i;
    Xs[r * XS + c] = (gi < lim) ? X[gi] : 0.f;
  }
  __syncthreads();
  int nl = t >> 2, ch = t & 3;
  float acc[CH];
#pragma unroll
  for (int j = 0; j < CH; ++j) acc[j] = 0.f;
  const float* xr = &Xs[nl * XS];
  const float* wc = &Ws[ch * CH];
  for (int k = 0; k < K; ++k) {
    float a = xr[k];
#pragma unroll
    for (int j = 0; j < CH; ++j) acc[j] = fmaf(a, wc[k * NOUT + j], acc[j]);
  }
  __syncthreads();
  int node = b0 + nl;
  float s = (node < n) ? dis[node] : 0.f;
  constexpr int ST = NOUT + 1;
#pragma unroll
  for (int j = 0; j < CH; ++j) {
    int jj = ch * CH + j;
    if (jj < NOUT) Xs[nl * ST + jj] = acc[j] * s;
  }
  __syncthreads();
  int gbase = b0 * NOUT;
  int glim = n * NOUT;
  for (int i = t; i < 64 * NOUT; i += 256) {
    int r = i / NOUT, c = i - r * NOUT;
    if (gbase + i < glim) {
      float v = Xs[r * ST + c];
      if (OUTFMT == 1)      ((u16*)G)[gbase + i] = f2bf(v);
      else if (OUTFMT == 2) ((u16*)G)[gbase + i] = __half_as_ushort(__float2half(v));
      else                  ((float*)G)[gbase + i] = v;
    }
  }
}

// ---------------- aggregation (hidden): 2 edges per wave-gather, 16 edges in flight ----------------
// wave = 2 halves of 32 lanes; half h owns edge i+2k+h; lane loads u32 = 2 bf16 feats.
__global__ __launch_bounds__(256) void agg_bf16_k(const u16* __restrict__ g,
                                                  const int* __restrict__ offs,
                                                  const int* __restrict__ adj,
                                                  const float* __restrict__ dis,
                                                  const float* __restrict__ bias,
                                                  float* __restrict__ out, int n) {
  int node = blockIdx.x * 4 + (threadIdx.x >> 6);
  int lane = threadIdx.x & 63;
  int half = lane >> 5, fl = lane & 31;
  if (node >= n) return;
  const u32* g32 = (const u32*)g;
  float acc0 = 0.f, acc1 = 0.f;
  int s = offs[node], e = offs[node + 1];
  int i = s;
  for (; i + 16 <= e; i += 16) {  // 8 gathers in flight per lane
    int r0 = adj[i + half];
    int r1 = adj[i + 2 + half];
    int r2 = adj[i + 4 + half];
    int r3 = adj[i + 6 + half];
    int r4 = adj[i + 8 + half];
    int r5 = adj[i + 10 + half];
    int r6 = adj[i + 12 + half];
    int r7 = adj[i + 14 + half];
    u32 v0 = g32[(r0 << 5) + fl];
    u32 v1 = g32[(r1 << 5) + fl];
    u32 v2 = g32[(r2 << 5) + fl];
    u32 v3 = g32[(r3 << 5) + fl];
    u32 v4 = g32[(r4 << 5) + fl];
    u32 v5 = g32[(r5 << 5) + fl];
    u32 v6 = g32[(r6 << 5) + fl];
    u32 v7 = g32[(r7 << 5) + fl];
    acc0 += ((bflo(v0) + bflo(v1)) + (bflo(v2) + bflo(v3))) +
            ((bflo(v4) + bflo(v5)) + (bflo(v6) + bflo(v7)));
    acc1 += ((bfhi(v0) + bfhi(v1)) + (bfhi(v2) + bfhi(v3))) +
            ((bfhi(v4) + bfhi(v5)) + (bfhi(v6) + bfhi(v7)));
  }
  for (; i + 8 <= e; i += 8) {
    int r0 = adj[i + half];
    int r1 = adj[i + 2 + half];
    int r2 = adj[i + 4 + half];
    int r3 = adj[i + 6 + half];
    u32 v0 = g32[(r0 << 5) + fl];
    u32 v1 = g32[(r1 << 5) + fl];
    u32 v2 = g32[(r2 << 5) + fl];
    u32 v3 = g32[(r3 << 5) + fl];
    acc0 += (bflo(v0) + bflo(v1)) + (bflo(v2) + bflo(v3));
    acc1 += (bfhi(v0) + bfhi(v1)) + (bfhi(v2) + bfhi(v3));
  }
  for (; i + 2 <= e; i += 2) {
    int r = adj[i + half];
    u32 v = g32[(r << 5) + fl];
    acc0 += bflo(v);
    acc1 += bfhi(v);
  }
  if (i < e) {  // odd tail edge: only half 0 counts it
    int r = adj[i];
    u32 v = g32[(r << 5) + fl];
    if (half == 0) { acc0 += bflo(v); acc1 += bfhi(v); }
  }
  acc0 += __shfl_xor(acc0, 32, 64);
  acc1 += __shfl_xor(acc1, 32, 64);
  u32 vs = g32[(node << 5) + fl];  // self loop (pre-scaled by dis[node])
  acc0 += bflo(vs);
  acc1 += bfhi(vs);
  float d = dis[node];
  float o0 = fmaxf(fmaf(d, acc0, bias[2 * fl]), 0.f);
  float o1 = fmaxf(fmaf(d, acc1, bias[2 * fl + 1]), 0.f);
  if (half == 0) {
    float2 st = {o0, o1};
    *(float2*)(out + node * 64 + 2 * fl) = st;
  }
}

// ---------------- aggregation (final, 18-wide fp16 table): 2 edges/gather, 16 in flight ----------------
// fp16 table = 3.6 MB -> L2-resident per XCD.
__global__ __launch_bounds__(256) void agg_f16o_k(const u16* __restrict__ g,
                                                  const int* __restrict__ offs,
                                                  const int* __restrict__ adj,
                                                  const float* __restrict__ dis,
                                                  const float* __restrict__ bias,
                                                  float* __restrict__ out, int n) {
  int node = blockIdx.x * 4 + (threadIdx.x >> 6);
  int lane = threadIdx.x & 63;
  int half = lane >> 5, fl = lane & 31;
  if (node >= n) return;
  const __half* gh = (const __half*)g;
  bool act = fl < 18;
  float acc = 0.f;
  int s = offs[node], e = offs[node + 1];
  int i = s;
  if (act) {
    for (; i + 16 <= e; i += 16) {
      int r0 = adj[i + half];
      int r1 = adj[i + 2 + half];
      int r2 = adj[i + 4 + half];
      int r3 = adj[i + 6 + half];
      int r4 = adj[i + 8 + half];
      int r5 = adj[i + 10 + half];
      int r6 = adj[i + 12 + half];
      int r7 = adj[i + 14 + half];
      float a0 = __half2float(gh[r0 * 18 + fl]);
      float a1 = __half2float(gh[r1 * 18 + fl]);
      float a2 = __half2float(gh[r2 * 18 + fl]);
      float a3 = __half2float(gh[r3 * 18 + fl]);
      float a4 = __half2float(gh[r4 * 18 + fl]);
      float a5 = __half2float(gh[r5 * 18 + fl]);
      float a6 = __half2float(gh[r6 * 18 + fl]);
      float a7 = __half2float(gh[r7 * 18 + fl]);
      acc += ((a0 + a1) + (a2 + a3)) + ((a4 + a5) + (a6 + a7));
    }
    for (; i + 8 <= e; i += 8) {
      int r0 = adj[i + half];
      int r1 = adj[i + 2 + half];
      int r2 = adj[i + 4 + half];
      int r3 = adj[i + 6 + half];
      float a0 = __half2float(gh[r0 * 18 + fl]);
      float a1 = __half2float(gh[r1 * 18 + fl]);
      float a2 = __half2float(gh[r2 * 18 + fl]);
      float a3 = __half2float(gh[r3 * 18 + fl]);
      acc += (a0 + a1) + (a2 + a3);
    }
    for (; i + 2 <= e; i += 2) acc += __half2float(gh[adj[i + half] * 18 + fl]);
    if (i < e && half == 0) acc += __half2float(gh[adj[i] * 18 + fl]);
  }
  acc += __shfl_xor(acc, 32, 64);  // all 64 lanes participate
  if (act) {
    acc += __half2float(gh[node * 18 + fl]);  // self loop
    float v = fmaf(dis[node], acc, bias[fl]);
    if (half == 0) out[node * 18 + fl] = v;
  }
}

// ---------------- launch ----------------

extern "C" void kernel_launch(void* const* d_in, const int* in_sizes, int n_in,
                              void* d_out, int out_size, void* d_ws, size_t ws_size,
                              hipStream_t stream) {
  const float* x  = (const float*)d_in[0];
  const int*   ei = (const int*)d_in[1];
  const float* W1 = (const float*)d_in[2];
  const float* b1 = (const float*)d_in[3];
  const float* W2 = (const float*)d_in[4];
  const float* b2 = (const float*)d_in[5];
  const float* W3 = (const float*)d_in[6];
  const float* b3 = (const float*)d_in[7];
  const float* Wo = (const float*)d_in[8];
  const float* bo = (const float*)d_in[9];
  float* out = (float*)d_out;

  const int N = NODES;
  const int E = in_sizes[1] / 2;
  const int* rowp = ei;
  const int* colp = ei + E;

  char* p = (char*)d_ws;
  auto alloc = [&](size_t bytes) {
    void* r = (void*)p;
    p += (bytes + 255) & ~(size_t)255;
    return r;
  };
  int*   bcnt  = (int*)alloc((size_t)NBKT * 4);
  int*   bcurs = (int*)alloc((size_t)NBKT * 4);
  int*   boffs = (int*)alloc((size_t)(NBKT + 1) * 4);
  float* dis   = (float*)alloc((size_t)N * 4);
  int*   offs  = (int*)alloc((size_t)(N + 1) * 4);
  int*   adj   = (int*)alloc((size_t)E * 4);
  // recs (E*4 = 12.8MB) dead after csr_k; alias with bf16 gather table (N*64*2 = 12.8MB)
  u32*   recs  = (u32*)alloc((size_t)N * 64 * 2);
  u16*   gb    = (u16*)recs;
  float* h     = (float*)alloc((size_t)N * 64 * 4);   // fp32 hidden activations
  u16*   g4    = (u16*)alloc((size_t)N * 18 * 2);    // fp16 gather table, final layer

  zero_k<<<(NBKT + 255) / 256, 256, 0, stream>>>(bcnt, NBKT);
  bucket_hist_k<<<(E + HCHUNK - 1) / HCHUNK, 256, 0, stream>>>(colp, bcnt, E);
  bscan_k<<<1, 256, 0, stream>>>(bcnt, boffs, bcurs, NBKT, E);
  bucket_fill_k<<<(E + FCHUNK - 1) / FCHUNK, 256, 0, stream>>>(rowp, colp, bcurs, recs, E);
  csr_k<<<NBKT, 256, 0, stream>>>(recs, boffs, offs, adj, dis, N, E);

  int gG = (N + 63) / 64;
  int gA = (N + 3) / 4;

  gemm_scale_k<100, 100, 64, 16, 1><<<gG, 256, 0, stream>>>(x, W1, dis, gb, N);
  agg_bf16_k<<<gA, 256, 0, stream>>>(gb, offs, adj, dis, b1, h, N);

  gemm_scale_k<64, 65, 64, 16, 1><<<gG, 256, 0, stream>>>(h, W2, dis, gb, N);
  agg_bf16_k<<<gA, 256, 0, stream>>>(gb, offs, adj, dis, b2, h, N);

  gemm_scale_k<64, 65, 64, 16, 1><<<gG, 256, 0, stream>>>(h, W3, dis, gb, N);
  agg_bf16_k<<<gA, 256, 0, stream>>>(gb, offs, adj, dis, b3, h, N);

  gemm_scale_k<64, 65, 18, 5, 2><<<gG, 256, 0, stream>>>(h, Wo, dis, g4, N);
  agg_f16o_k<<<gA, 256, 0, stream>>>(g4, offs, adj, dis, bo, out, N);
}